// Round 7
// baseline (222.929 us; speedup 1.0000x reference)
//
#include <hip/hip_runtime.h>

#define D 128
#define SCAN_BLK 1024
#define BM 64
#define KC 32

using short8 = __attribute__((ext_vector_type(8))) short;
using floatx4 = __attribute__((ext_vector_type(4))) float;

__device__ __forceinline__ unsigned int f2bf(unsigned int b) {
    return (b + 0x7fffu + ((b >> 16) & 1u)) >> 16;  // RNE fp32->bf16 (as u16)
}

// ---------- W transpose (tier-3 VALU path) ----------
__global__ void transpose_w_kernel(const float* __restrict__ w, float* __restrict__ wt) {
    int t = blockIdx.x * 256 + threadIdx.x;
    if (t < D * D) {
        int o = t >> 7;
        int k = t & 127;
        wt[k * D + o] = w[t];
    }
}

// ---------- W -> bf16, XOR-swizzled [n][k] table for MFMA B-frags ----------
__global__ void prep_wbfs_kernel(const float* __restrict__ w, unsigned short* __restrict__ wbfs) {
    int t = blockIdx.x * 256 + threadIdx.x;
    if (t < D * D) {
        int n = t >> 7, k = t & 127;
        wbfs[n * 128 + (k ^ ((n & 7) << 3))] = (unsigned short)f2bf(__float_as_uint(w[t]));
    }
}

// ---------- x -> bf16 (RNE), packed 2 per uint ----------
__global__ __launch_bounds__(256) void x_to_bf16_kernel(const float* __restrict__ x,
                                                        unsigned int* __restrict__ xbf,
                                                        long long nvec) {
    long long i = (long long)blockIdx.x * 256 + threadIdx.x;
    long long stride = (long long)gridDim.x * 256;
    for (; i < nvec; i += stride) {
        float4 v = ((const float4*)x)[i];
        unsigned int b0 = f2bf(__float_as_uint(v.x)), b1 = f2bf(__float_as_uint(v.y));
        unsigned int b2 = f2bf(__float_as_uint(v.z)), b3 = f2bf(__float_as_uint(v.w));
        ((uint2*)xbf)[i] = make_uint2(b0 | (b1 << 16), b2 | (b3 << 16));
    }
}

// ---------- hist + rank (rank used only by non-binned fallback) ----------
__global__ void hist_rank_kernel(const int* __restrict__ ei, int* deg,
                                 unsigned short* __restrict__ rank, int E) {
    int e = blockIdx.x * 256 + threadIdx.x;
    if (e < E) rank[e] = (unsigned short)atomicAdd(&deg[ei[e]], 1);
}

// ---------- scans ----------
__global__ __launch_bounds__(SCAN_BLK) void scan_blocks_kernel(const int* __restrict__ deg,
                                                               int* inscan, int* blksum, int n) {
    __shared__ int s[SCAN_BLK];
    int gid = blockIdx.x * SCAN_BLK + threadIdx.x;
    int v = (gid < n) ? deg[gid] : 0;
    s[threadIdx.x] = v;
    __syncthreads();
    for (int d = 1; d < SCAN_BLK; d <<= 1) {
        int t = (threadIdx.x >= d) ? s[threadIdx.x - d] : 0;
        __syncthreads();
        s[threadIdx.x] += t;
        __syncthreads();
    }
    if (gid < n) inscan[gid] = s[threadIdx.x];
    if (threadIdx.x == SCAN_BLK - 1) blksum[blockIdx.x] = s[SCAN_BLK - 1];
}

__global__ __launch_bounds__(128) void scan_sums_kernel(const int* __restrict__ blksum,
                                                        int* blkoff, int nblk) {
    __shared__ int s[128];
    int v = (threadIdx.x < nblk) ? blksum[threadIdx.x] : 0;
    s[threadIdx.x] = v;
    __syncthreads();
    for (int d = 1; d < 128; d <<= 1) {
        int t = (threadIdx.x >= d) ? s[threadIdx.x - d] : 0;
        __syncthreads();
        s[threadIdx.x] += t;
        __syncthreads();
    }
    if (threadIdx.x < nblk) blkoff[threadIdx.x] = s[threadIdx.x] - v;
}

// off[] + per-bucket cursor init (bcursor[b] = off[b*256])
__global__ void finalize_offsets_kernel(const int* __restrict__ deg,
                                        const int* __restrict__ inscan,
                                        const int* __restrict__ blkoff,
                                        int* off, int* bcursor, int n, int E) {
    int gid = blockIdx.x * 256 + threadIdx.x;
    if (gid < n) {
        int o = blkoff[gid >> 10] + inscan[gid] - deg[gid];
        off[gid] = o;
        if ((gid & 255) == 0) bcursor[gid >> 8] = o;
    }
    if (gid == 0) off[n] = E;
}

// ---------- binned reorder pass A: edges -> 256-node buckets ----------
// 512 thr, 8192 edges/block.  Per-block contiguous runs per bucket -> low write amp.
__global__ __launch_bounds__(512) void binA_kernel(const int* __restrict__ ei,
                                                   const float* __restrict__ ev,
                                                   int* bcursor, int2* __restrict__ ebin,
                                                   int E, int NB) {
    __shared__ int hist[512];
    __shared__ int base[512];
    __shared__ int cnt2[512];
    int tid = threadIdx.x;
    hist[tid] = 0;
    cnt2[tid] = 0;
    __syncthreads();
    int e0 = blockIdx.x * 8192;
#pragma unroll
    for (int i = 0; i < 16; ++i) {
        int e = e0 + i * 512 + tid;
        if (e < E) atomicAdd(&hist[((unsigned)ei[e]) >> 8], 1);
    }
    __syncthreads();
    if (tid < NB && hist[tid] > 0) base[tid] = atomicAdd(&bcursor[tid], hist[tid]);
    __syncthreads();
#pragma unroll
    for (int i = 0; i < 16; ++i) {
        int e = e0 + i * 512 + tid;
        if (e < E) {
            int dst = ei[e];
            int b = ((unsigned)dst) >> 8;
            int pos = base[b] + atomicAdd(&cnt2[b], 1);
            // pack: src (<2^24) | low-8 of dst in top byte
            ebin[pos] = make_int2(ei[E + e] | ((dst & 255) << 24), __float_as_int(ev[e]));
        }
    }
}

// ---------- binned reorder pass B: bucket -> exact CSR position ----------
// One block per bucket; writes confined to the bucket's contiguous srt window.
__global__ __launch_bounds__(512) void binB_kernel(const int* __restrict__ off,
                                                   const int2* __restrict__ ebin,
                                                   int2* __restrict__ srt, int N) {
    __shared__ int cnt[256];
    __shared__ int offl[256];
    int b = blockIdx.x;
    int tid = threadIdx.x;
    int node0 = b << 8;
    if (tid < 256) {
        cnt[tid] = 0;
        int nd = node0 + tid;
        offl[tid] = (nd < N) ? off[nd] : 0;
    }
    __syncthreads();
    int nend = node0 + 256 < N ? node0 + 256 : N;
    int start = off[node0];
    int end = off[nend];
    for (int p = start + tid; p < end; p += 512) {
        int2 eb = ebin[p];
        int dl = ((unsigned)eb.x) >> 24;
        int pos = offl[dl] + atomicAdd(&cnt[dl], 1);
        srt[pos] = make_int2(eb.x & 0x00FFFFFF, eb.y);
    }
}

// ---------- non-binned reorder (fallback): pos = off[dst] + rank[e] ----------
__global__ void edge_scatter2_kernel(const int* __restrict__ ei, const float* __restrict__ ev,
                                     const int* __restrict__ off,
                                     const unsigned short* __restrict__ rank,
                                     int2* __restrict__ srt, int E) {
    int e = blockIdx.x * 256 + threadIdx.x;
    if (e < E) {
        int dst = ei[e];
        int pos = off[dst] + (int)rank[e];
        srt[pos] = make_int2(ei[E + e], __float_as_int(ev[e]));
    }
}

// ---------- gather from bf16 table; AGGBF: write packed bf16 agg ----------
template <bool AGGBF>
__global__ __launch_bounds__(256) void gather_bf16_kernel(const int* __restrict__ off,
                                                          const int2* __restrict__ srt,
                                                          const unsigned int* __restrict__ xbf,
                                                          float* __restrict__ out,
                                                          unsigned int* __restrict__ aggbf,
                                                          int N) {
    int lane = threadIdx.x & 63;
    int wid = blockIdx.x * 4 + (threadIdx.x >> 6);
    if (wid >= N) return;
    int beg = off[wid], end = off[wid + 1];
    float2 acc = make_float2(0.f, 0.f);
    int e = beg;
    for (; e + 3 < end; e += 4) {
        int2 s0 = srt[e], s1 = srt[e + 1], s2 = srt[e + 2], s3 = srt[e + 3];
        unsigned int u0 = xbf[(size_t)s0.x * 64 + lane];
        unsigned int u1 = xbf[(size_t)s1.x * 64 + lane];
        unsigned int u2 = xbf[(size_t)s2.x * 64 + lane];
        unsigned int u3 = xbf[(size_t)s3.x * 64 + lane];
        float v0 = __int_as_float(s0.y), v1 = __int_as_float(s1.y);
        float v2 = __int_as_float(s2.y), v3 = __int_as_float(s3.y);
        acc.x = fmaf(v0, __uint_as_float(u0 << 16), acc.x);
        acc.y = fmaf(v0, __uint_as_float(u0 & 0xffff0000u), acc.y);
        acc.x = fmaf(v1, __uint_as_float(u1 << 16), acc.x);
        acc.y = fmaf(v1, __uint_as_float(u1 & 0xffff0000u), acc.y);
        acc.x = fmaf(v2, __uint_as_float(u2 << 16), acc.x);
        acc.y = fmaf(v2, __uint_as_float(u2 & 0xffff0000u), acc.y);
        acc.x = fmaf(v3, __uint_as_float(u3 << 16), acc.x);
        acc.y = fmaf(v3, __uint_as_float(u3 & 0xffff0000u), acc.y);
    }
    for (; e < end; ++e) {
        int2 sv = srt[e];
        unsigned int u = xbf[(size_t)sv.x * 64 + lane];
        float v = __int_as_float(sv.y);
        acc.x = fmaf(v, __uint_as_float(u << 16), acc.x);
        acc.y = fmaf(v, __uint_as_float(u & 0xffff0000u), acc.y);
    }
    if (AGGBF) {
        unsigned int pk = f2bf(__float_as_uint(acc.x)) | (f2bf(__float_as_uint(acc.y)) << 16);
        aggbf[(size_t)wid * 64 + lane] = pk;
    } else {
        *(float2*)&out[(size_t)wid * D + lane * 2] = acc;
    }
}

// ---------- fp32 gather (tier-2) ----------
__global__ __launch_bounds__(256) void gather_kernel(const int* __restrict__ off,
                                                     const int2* __restrict__ srt,
                                                     const float* __restrict__ x,
                                                     float* __restrict__ out, int N) {
    int lane = threadIdx.x & 63;
    int wid = blockIdx.x * 4 + (threadIdx.x >> 6);
    if (wid >= N) return;
    int beg = off[wid], end = off[wid + 1];
    float2 acc = make_float2(0.f, 0.f);
    for (int e = beg; e < end; ++e) {
        int2 sv = srt[e];
        float2 xv = *(const float2*)&x[(size_t)sv.x * D + lane * 2];
        float v = __int_as_float(sv.y);
        acc.x = fmaf(v, xv.x, acc.x);
        acc.y = fmaf(v, xv.y, acc.y);
    }
    *(float2*)&out[(size_t)wid * D + lane * 2] = acc;
}

// ---------- MFMA linear, A from fp32 io (in-place) ----------
__global__ __launch_bounds__(256) void linear_mfma_kernel(float* io,
                                                          const unsigned short* __restrict__ wbfs,
                                                          int N) {
    __shared__ __align__(16) unsigned short sW[D * D];
    __shared__ __align__(16) unsigned short sA[BM * D];
    int t = threadIdx.x;
    int row0 = blockIdx.x * BM;
    {
        const uint4* src = (const uint4*)wbfs;
        uint4* dst = (uint4*)sW;
#pragma unroll
        for (int i = 0; i < 8; ++i) dst[i * 256 + t] = src[i * 256 + t];
    }
#pragma unroll
    for (int it = 0; it < 8; ++it) {
        int idx = it * 1024 + t * 4;
        int m = idx >> 7;
        int k0 = idx & 127;
        int r = row0 + m;
        int rcl = r < N ? r : N - 1;
        float4 v = *(const float4*)&io[(size_t)rcl * D + k0];
        unsigned int b0 = f2bf(__float_as_uint(v.x)), b1 = f2bf(__float_as_uint(v.y));
        unsigned int b2 = f2bf(__float_as_uint(v.z)), b3 = f2bf(__float_as_uint(v.w));
        int byteoff = m * 256 + ((k0 * 2) ^ ((m & 7) << 4));
        *(uint2*)((char*)sA + byteoff) = make_uint2(b0 | (b1 << 16), b2 | (b3 << 16));
    }
    __syncthreads();

    int lane = t & 63;
    int w = t >> 6;
    int lm = 16 * w + (lane & 15);
    int ln = lane & 15;
    int kg = lane >> 4;

    floatx4 acc[8];
#pragma unroll
    for (int nt = 0; nt < 8; ++nt) acc[nt] = (floatx4){0.f, 0.f, 0.f, 0.f};

#pragma unroll
    for (int ks = 0; ks < 4; ++ks) {
        int kbyte = ks * 64 + kg * 16;
        short8 a = *(const short8*)((const char*)sA + lm * 256 + (kbyte ^ ((lm & 7) << 4)));
#pragma unroll
        for (int nt = 0; nt < 8; ++nt) {
            int n = nt * 16 + ln;
            short8 b = *(const short8*)((const char*)sW + n * 256 + (kbyte ^ ((n & 7) << 4)));
            acc[nt] = __builtin_amdgcn_mfma_f32_16x16x32_bf16(a, b, acc[nt], 0, 0, 0);
        }
    }

    int rbase = row0 + 16 * w + 4 * kg;
#pragma unroll
    for (int nt = 0; nt < 8; ++nt) {
#pragma unroll
        for (int r = 0; r < 4; ++r) {
            int row = rbase + r;
            if (row < N) io[(size_t)row * D + nt * 16 + ln] = acc[nt][r];
        }
    }
}

// ---------- MFMA linear, A from packed-bf16 agg -> writes d_out ----------
__global__ __launch_bounds__(256) void linear_mfma_bf_kernel(const unsigned int* __restrict__ aggbf,
                                                             const unsigned short* __restrict__ wbfs,
                                                             float* __restrict__ out, int N) {
    __shared__ __align__(16) unsigned short sW[D * D];
    __shared__ __align__(16) unsigned short sA[BM * D];
    int t = threadIdx.x;
    int row0 = blockIdx.x * BM;
    {
        const uint4* src = (const uint4*)wbfs;
        uint4* dst = (uint4*)sW;
#pragma unroll
        for (int i = 0; i < 8; ++i) dst[i * 256 + t] = src[i * 256 + t];
    }
#pragma unroll
    for (int it = 0; it < 4; ++it) {
        int iv = it * 256 + t;  // uint4 id 0..1023
        int m = iv >> 4;        // row in tile
        int q = iv & 15;        // 16B chunk within row
        int r = row0 + m;
        int rcl = r < N ? r : N - 1;
        uint4 v = *(const uint4*)&aggbf[(size_t)rcl * 64 + q * 4];
        *(uint4*)((char*)sA + m * 256 + ((q * 16) ^ ((m & 7) << 4))) = v;
    }
    __syncthreads();

    int lane = t & 63;
    int w = t >> 6;
    int lm = 16 * w + (lane & 15);
    int ln = lane & 15;
    int kg = lane >> 4;

    floatx4 acc[8];
#pragma unroll
    for (int nt = 0; nt < 8; ++nt) acc[nt] = (floatx4){0.f, 0.f, 0.f, 0.f};

#pragma unroll
    for (int ks = 0; ks < 4; ++ks) {
        int kbyte = ks * 64 + kg * 16;
        short8 a = *(const short8*)((const char*)sA + lm * 256 + (kbyte ^ ((lm & 7) << 4)));
#pragma unroll
        for (int nt = 0; nt < 8; ++nt) {
            int n = nt * 16 + ln;
            short8 b = *(const short8*)((const char*)sW + n * 256 + (kbyte ^ ((n & 7) << 4)));
            acc[nt] = __builtin_amdgcn_mfma_f32_16x16x32_bf16(a, b, acc[nt], 0, 0, 0);
        }
    }

    int rbase = row0 + 16 * w + 4 * kg;
#pragma unroll
    for (int nt = 0; nt < 8; ++nt) {
#pragma unroll
        for (int r = 0; r < 4; ++r) {
            int row = rbase + r;
            if (row < N) out[(size_t)row * D + nt * 16 + ln] = acc[nt][r];
        }
    }
}

// ---------- VALU tiled GEMM (tier-3) ----------
__global__ __launch_bounds__(256) void linear_tiled_kernel(float* io,
                                                           const float* __restrict__ wt,
                                                           int N) {
    __shared__ float sA[KC][BM + 4];
    __shared__ float sW2[KC][D];
    int t = threadIdx.x;
    int tc = t & 15;
    int tr = t >> 4;
    int row0 = blockIdx.x * BM;

    float acc[4][8];
#pragma unroll
    for (int i = 0; i < 4; ++i)
#pragma unroll
        for (int j = 0; j < 8; ++j) acc[i][j] = 0.f;

    int ldA_r = t >> 3;
    int ldA_k = (t & 7) * 4;
    int ldW_k = t >> 5;
    int ldW_c = (t & 31) * 4;

    for (int kc = 0; kc < D; kc += KC) {
#pragma unroll
        for (int rr = 0; rr < BM; rr += 32) {
            int r = row0 + ldA_r + rr;
            int rcl = r < N ? r : N - 1;
            float4 v = *(const float4*)&io[(size_t)rcl * D + kc + ldA_k];
            sA[ldA_k + 0][ldA_r + rr] = v.x;
            sA[ldA_k + 1][ldA_r + rr] = v.y;
            sA[ldA_k + 2][ldA_r + rr] = v.z;
            sA[ldA_k + 3][ldA_r + rr] = v.w;
        }
#pragma unroll
        for (int kk = 0; kk < KC; kk += 8)
            *(float4*)&sW2[ldW_k + kk][ldW_c] =
                *(const float4*)&wt[(size_t)(kc + ldW_k + kk) * D + ldW_c];
        __syncthreads();

#pragma unroll 8
        for (int k = 0; k < KC; ++k) {
            float4 a = *(const float4*)&sA[k][tr * 4];
            float4 w0 = *(const float4*)&sW2[k][tc * 8];
            float4 w1 = *(const float4*)&sW2[k][tc * 8 + 4];
            float av[4] = {a.x, a.y, a.z, a.w};
            float wv[8] = {w0.x, w0.y, w0.z, w0.w, w1.x, w1.y, w1.z, w1.w};
#pragma unroll
            for (int i = 0; i < 4; ++i)
#pragma unroll
                for (int j = 0; j < 8; ++j)
                    acc[i][j] = fmaf(av[i], wv[j], acc[i][j]);
        }
        __syncthreads();
    }

#pragma unroll
    for (int i = 0; i < 4; ++i) {
        int r = row0 + tr * 4 + i;
        if (r < N) {
            *(float4*)&io[(size_t)r * D + tc * 8] = *(float4*)&acc[i][0];
            *(float4*)&io[(size_t)r * D + tc * 8 + 4] = *(float4*)&acc[i][4];
        }
    }
}

// ---------- tier-3 fallback (atomic scatter) ----------
__global__ __launch_bounds__(256) void scatter_kernel(const int* __restrict__ ei,
                                                      const float* __restrict__ ev,
                                                      const float* __restrict__ x,
                                                      float* agg, int E) {
    int lane = threadIdx.x & 63;
    long long wid = (long long)blockIdx.x * 4 + (threadIdx.x >> 6);
    long long nw = (long long)gridDim.x * 4;
    for (long long e = wid; e < E; e += nw) {
        int i = ei[e];
        int j = ei[(long long)E + e];
        float v = ev[e];
        float2 xv = *(const float2*)&x[(size_t)j * D + lane * 2];
        float* op = &agg[(size_t)i * D + lane * 2];
        unsafeAtomicAdd(&op[0], v * xv.x);
        unsafeAtomicAdd(&op[1], v * xv.y);
    }
}

extern "C" void kernel_launch(void* const* d_in, const int* in_sizes, int n_in,
                              void* d_out, int out_size, void* d_ws, size_t ws_size,
                              hipStream_t stream) {
    const float* x = (const float*)d_in[0];
    const float* w = (const float*)d_in[1];
    const int* ei = (const int*)d_in[2];   // [2,E] int32 (dst row, then src row)
    const float* ev = (const float*)d_in[3];

    int N = in_sizes[0] / D;
    int E = in_sizes[3];
    int nblk = (N + SCAN_BLK - 1) / SCAN_BLK;
    int NB = (N + 255) >> 8;

    float* out = (float*)d_out;

    // workspace layout (progressive tiers)
    char* p = (char*)d_ws;
    float* wt = (float*)p;            p += (size_t)D * D * sizeof(float);
    unsigned short* wbfs = (unsigned short*)p;  p += (size_t)D * D * sizeof(unsigned short);
    int* deg = (int*)p;               p += (size_t)N * sizeof(int);
    int* inscan = (int*)p;            p += (size_t)N * sizeof(int);
    int* off = (int*)p;               p += (size_t)(N + 1) * sizeof(int);
    int* blksum = (int*)p;            p += (size_t)nblk * sizeof(int);
    int* blkoff = (int*)p;            p += (size_t)nblk * sizeof(int);
    int* bcursor = (int*)p;           p += 512 * sizeof(int);
    p = (char*)(((uintptr_t)p + 255) & ~(uintptr_t)255);
    unsigned short* rank = (unsigned short*)p;  p += (size_t)E * sizeof(unsigned short);
    p = (char*)(((uintptr_t)p + 255) & ~(uintptr_t)255);
    int2* srt = (int2*)p;             p += (size_t)E * sizeof(int2);
    size_t needed_t2 = (size_t)(p - (char*)d_ws);
    p = (char*)(((uintptr_t)p + 255) & ~(uintptr_t)255);
    unsigned int* xbf = (unsigned int*)p;  p += (size_t)N * (D / 2) * sizeof(unsigned int);
    size_t needed_t1 = (size_t)(p - (char*)d_ws);
    p = (char*)(((uintptr_t)p + 255) & ~(uintptr_t)255);
    int2* ebin = (int2*)p;            p += (size_t)E * sizeof(int2);
    size_t needed_tA = (size_t)(p - (char*)d_ws);
    p = (char*)(((uintptr_t)p + 255) & ~(uintptr_t)255);
    unsigned int* aggbf = (unsigned int*)p;  p += (size_t)N * (D / 2) * sizeof(unsigned int);
    size_t needed_tB = (size_t)(p - (char*)d_ws);

    int gemm_blocks = (N + BM - 1) / BM;

    if (ws_size >= needed_t2) {
        bool bf16 = (ws_size >= needed_t1);
        // binned path requires bucket count <= 512 and src < 2^24
        bool binned = (ws_size >= needed_tA) && (N <= 131072) && (NB <= 512);
        bool aggb = bf16 && binned && (ws_size >= needed_tB);

        prep_wbfs_kernel<<<(D * D + 255) / 256, 256, 0, stream>>>(w, wbfs);
        hipMemsetAsync(deg, 0, (size_t)N * sizeof(int), stream);
        if (bf16)
            x_to_bf16_kernel<<<2048, 256, 0, stream>>>(x, xbf, (long long)N * D / 4);
        hist_rank_kernel<<<(E + 255) / 256, 256, 0, stream>>>(ei, deg, rank, E);
        scan_blocks_kernel<<<nblk, SCAN_BLK, 0, stream>>>(deg, inscan, blksum, N);
        scan_sums_kernel<<<1, 128, 0, stream>>>(blksum, blkoff, nblk);
        finalize_offsets_kernel<<<(N + 255) / 256, 256, 0, stream>>>(deg, inscan, blkoff,
                                                                     off, bcursor, N, E);
        if (binned) {
            binA_kernel<<<(E + 8191) / 8192, 512, 0, stream>>>(ei, ev, bcursor, ebin, E, NB);
            binB_kernel<<<NB, 512, 0, stream>>>(off, ebin, srt, N);
        } else {
            edge_scatter2_kernel<<<(E + 255) / 256, 256, 0, stream>>>(ei, ev, off, rank, srt, E);
        }
        if (aggb) {
            gather_bf16_kernel<true><<<(N + 3) / 4, 256, 0, stream>>>(off, srt, xbf, out,
                                                                      aggbf, N);
            linear_mfma_bf_kernel<<<gemm_blocks, 256, 0, stream>>>(aggbf, wbfs, out, N);
        } else if (bf16) {
            gather_bf16_kernel<false><<<(N + 3) / 4, 256, 0, stream>>>(off, srt, xbf, out,
                                                                       aggbf, N);
            linear_mfma_kernel<<<gemm_blocks, 256, 0, stream>>>(out, wbfs, N);
        } else {
            gather_kernel<<<(N + 3) / 4, 256, 0, stream>>>(off, srt, x, out, N);
            linear_mfma_kernel<<<gemm_blocks, 256, 0, stream>>>(out, wbfs, N);
        }
    } else {
        transpose_w_kernel<<<(D * D + 255) / 256, 256, 0, stream>>>(w, wt);
        hipMemsetAsync(d_out, 0, (size_t)out_size * sizeof(float), stream);
        scatter_kernel<<<4096, 256, 0, stream>>>(ei, ev, x, out, E);
        linear_tiled_kernel<<<gemm_blocks, 256, 0, stream>>>(out, wt, N);
    }
}